// Round 2
// baseline (569.064 us; speedup 1.0000x reference)
//
#include <hip/hip_runtime.h>
#include <stdint.h>
#include <math.h>

#define NAG 8192
#define NB  144          // 128 feats + deg col(128) + pad to 9*16
#define LDA 72           // LDS row stride for A tile (64 + 8 pad)
#define LDB 72           // LDS row stride for B tile

typedef __attribute__((ext_vector_type(8))) short short8;
typedef __attribute__((ext_vector_type(4))) float floatx4;

__device__ __forceinline__ float bf2f(unsigned short u) {
    union { uint32_t i; float f; } v; v.i = ((uint32_t)u) << 16; return v.f;
}
__device__ __forceinline__ unsigned short f2bf(float f) {
    union { float f; uint32_t i; } v; v.f = f;
    uint32_t x = v.i;
    return (unsigned short)((x + 0x7FFFu + ((x >> 16) & 1u)) >> 16);  // RNE
}

// ---------------- Kernel 0: zero C, detect float storage dtype from W1 raw bits ----------------
// fp32 storage: low halves of floats are mantissa noise -> some short decodes to |bf16|>1e6 or NaN.
// bf16 storage: W1 in [-0.125,0.125] -> all decode small. flag=1 means fp32.
__global__ __launch_bounds__(256) void k0_init(
    float* __restrict__ C, int* __restrict__ flag,
    const unsigned short* __restrict__ W1raw)
{
    size_t i = ((size_t)blockIdx.x * 256 + threadIdx.x) * 4;   // 1152*256*4 = 8192*144 exactly
    *reinterpret_cast<float4*>(C + i) = make_float4(0.f, 0.f, 0.f, 0.f);
    if (blockIdx.x == 0 && threadIdx.x < 64) {
        int big = 0;
        #pragma unroll
        for (int j = 0; j < 8; ++j) {
            float v = bf2f(W1raw[threadIdx.x * 8 + j]);
            if (!(fabsf(v) <= 1e6f)) big = 1;   // catches huge and NaN
        }
        unsigned long long m = __ballot(big);
        if (threadIdx.x == 0) *flag = (m != 0ull) ? 1 : 0;
    }
}

// ---------------- Kernel 1: h = tanh(obs@W1+b1); write h_f32 and hT_bf16 ----------------
__global__ __launch_bounds__(256) void k1_encode(
    const void* __restrict__ obs,   // [8192][64] fp32 or bf16
    const void* __restrict__ W1,    // [64][128]
    const void* __restrict__ b1,    // [128]
    const int* __restrict__ flag,
    float* __restrict__ h_f32,      // [8192][128]
    unsigned short* __restrict__ hT)// [144][8192] bf16 (row128=ones, 129..143=0)
{
    __shared__ float obs_lds[32][68];
    __shared__ unsigned short ht_lds[128][33];
    const int t = threadIdx.x;
    const int abase = blockIdx.x * 32;
    const bool isf = (*flag != 0);

    {   // stage obs tile 32x64, 8 scalar elems/thread (explicit branch: no speculative OOB loads)
        int a = t >> 3, c0 = (t & 7) * 8;
        if (isf) {
            const float* p = (const float*)obs;
            #pragma unroll
            for (int j = 0; j < 8; ++j)
                obs_lds[a][c0 + j] = p[(size_t)(abase + a) * 64 + c0 + j];
        } else {
            const unsigned short* p = (const unsigned short*)obs;
            #pragma unroll
            for (int j = 0; j < 8; ++j)
                obs_lds[a][c0 + j] = bf2f(p[(size_t)(abase + a) * 64 + c0 + j]);
        }
    }
    __syncthreads();

    const int o = t & 127;
    const int half = t >> 7;          // wave-uniform
    float acc[16];
    if (isf) {
        const float* Wp = (const float*)W1;
        float bias = ((const float*)b1)[o];
        #pragma unroll
        for (int i = 0; i < 16; ++i) acc[i] = bias;
        for (int k = 0; k < 64; ++k) {
            float w = Wp[k * 128 + o];
            #pragma unroll
            for (int i = 0; i < 16; ++i)
                acc[i] = fmaf(obs_lds[half * 16 + i][k], w, acc[i]);
        }
    } else {
        const unsigned short* Wp = (const unsigned short*)W1;
        float bias = bf2f(((const unsigned short*)b1)[o]);
        #pragma unroll
        for (int i = 0; i < 16; ++i) acc[i] = bias;
        for (int k = 0; k < 64; ++k) {
            float w = bf2f(Wp[k * 128 + o]);
            #pragma unroll
            for (int i = 0; i < 16; ++i)
                acc[i] = fmaf(obs_lds[half * 16 + i][k], w, acc[i]);
        }
    }
    #pragma unroll
    for (int i = 0; i < 16; ++i) {
        float th = tanhf(acc[i]);
        int a = half * 16 + i;
        h_f32[(size_t)(abase + a) * 128 + o] = th;
        ht_lds[o][a] = f2bf(th);
    }
    __syncthreads();

    // write hT rows (coalesced 64B chunks)
    for (int p = 0; p < 18; ++p) {
        int n = p * 8 + (t >> 5);
        int a = t & 31;
        unsigned short v;
        if (n < 128)       v = ht_lds[n][a];
        else if (n == 128) v = 0x3F80;     // 1.0 bf16 -> deg column
        else               v = 0;
        hT[(size_t)n * NAG + abase + a] = v;
    }
}

// ---------------- Kernel 2: C += adj[:, kslice] @ [h|1|0]  (bf16 MFMA, atomic accumulate) ----------------
__global__ __launch_bounds__(256) void k2_msggemm(
    const int* __restrict__ adj,              // [8192][8192] int32 {0,1}
    const unsigned short* __restrict__ hT,    // [144][8192] bf16
    float* __restrict__ C)                    // [8192][144] fp32, pre-zeroed
{
    __shared__ __align__(16) unsigned short Alds[64 * LDA];
    __shared__ __align__(16) unsigned short Blds[NB * LDB];
    const int t = threadIdx.x;
    const int mtile = blockIdx.x & 127;
    const int ks = blockIdx.x >> 7;
    const int row0 = mtile * 64;
    const int kbeg = ks * 2048;

    const int wave = t >> 6, lane = t & 63;
    const int fm = lane & 15, quad = lane >> 4;

    floatx4 acc[9];
    #pragma unroll
    for (int i = 0; i < 9; ++i) acc[i] = (floatx4)0.f;

    const int ar = t >> 2, aq = t & 3;    // A staging: row, quarter
    const int bln = t & 7, brow = t >> 3; // B staging: lane-in-row, row-offset

    for (int kb = kbeg; kb < kbeg + 2048; kb += 64) {
        // stage A: 64 rows x 64 int32 -> bf16 (0/1 exact via *0x3F80)
        const int* rowp = adj + (size_t)(row0 + ar) * NAG + kb;
        #pragma unroll
        for (int i = 0; i < 4; ++i) {
            int c = i * 16 + aq * 4;
            int4 v = *reinterpret_cast<const int4*>(rowp + c);
            uint32_t d0 = ((uint32_t)v.x | ((uint32_t)v.y << 16)) * 0x3F80u;
            uint32_t d1 = ((uint32_t)v.z | ((uint32_t)v.w << 16)) * 0x3F80u;
            *reinterpret_cast<uint2*>(&Alds[ar * LDA + c]) = make_uint2(d0, d1);
        }
        // stage B: 144 rows x 64 bf16 (k-contiguous, from hT)
        #pragma unroll
        for (int p = 0; p < 5; ++p) {
            int n = p * 32 + brow;
            if (n < NB) {
                uint4 v = *reinterpret_cast<const uint4*>(hT + (size_t)n * NAG + kb + bln * 8);
                *reinterpret_cast<uint4*>(&Blds[n * LDB + bln * 8]) = v;
            }
        }
        __syncthreads();
        #pragma unroll
        for (int kk = 0; kk < 64; kk += 32) {
            short8 af = *reinterpret_cast<const short8*>(&Alds[(wave * 16 + fm) * LDA + kk + quad * 8]);
            #pragma unroll
            for (int nt = 0; nt < 9; ++nt) {
                short8 bf = *reinterpret_cast<const short8*>(&Blds[(nt * 16 + fm) * LDB + kk + quad * 8]);
                acc[nt] = __builtin_amdgcn_mfma_f32_16x16x32_bf16(af, bf, acc[nt], 0, 0, 0);
            }
        }
        __syncthreads();
    }
    // epilogue: C/D layout col=lane&15, row=quad*4+reg; accumulate across 4 K-splits atomically
    #pragma unroll
    for (int nt = 0; nt < 9; ++nt) {
        int col = nt * 16 + fm;
        #pragma unroll
        for (int r = 0; r < 4; ++r) {
            int row = row0 + wave * 16 + quad * 4 + r;
            atomicAdd(&C[(size_t)row * NB + col], acc[nt][r]);
        }
    }
}

// ---------------- Kernel 3: msg=sum/deg, actor MLP, dtype-adaptive weights & output ----------------
__global__ __launch_bounds__(256) void k3_actor(
    const float* __restrict__ h_f32,          // [8192][128]
    const float* __restrict__ C,              // [8192][144] fp32 sums
    const void* __restrict__ W2,              // [256][128]
    const void* __restrict__ b2,              // [128]
    const void* __restrict__ W3,              // [128][16]
    const void* __restrict__ b3,              // [16]
    const int* __restrict__ flag,
    void* __restrict__ out)                   // [8192][16]
{
    __shared__ float comb[32][256];
    __shared__ float hid[32][132];
    __shared__ float inv_lds[32];
    const int t = threadIdx.x;
    const int abase = blockIdx.x * 32;
    const bool isf = (*flag != 0);

    if (t < 32) {
        float deg = C[(size_t)(abase + t) * NB + 128];
        inv_lds[t] = 1.0f / fmaxf(deg, 1.0f);
    }
    __syncthreads();
    for (int a = 0; a < 32; ++a) {
        int i = abase + a;
        if (t < 128) {
            comb[a][t] = h_f32[(size_t)i * 128 + t];
        } else {
            int f = t - 128;
            comb[a][128 + f] = C[(size_t)i * NB + f] * inv_lds[a];
        }
    }
    __syncthreads();

    const int o = t & 127, half = t >> 7;
    float acc[16];
    if (isf) {
        const float* Wp = (const float*)W2;
        float bias = ((const float*)b2)[o];
        #pragma unroll
        for (int i = 0; i < 16; ++i) acc[i] = bias;
        for (int c = 0; c < 256; ++c) {
            float w = Wp[c * 128 + o];
            #pragma unroll
            for (int i = 0; i < 16; ++i)
                acc[i] = fmaf(comb[half * 16 + i][c], w, acc[i]);
        }
    } else {
        const unsigned short* Wp = (const unsigned short*)W2;
        float bias = bf2f(((const unsigned short*)b2)[o]);
        #pragma unroll
        for (int i = 0; i < 16; ++i) acc[i] = bias;
        for (int c = 0; c < 256; ++c) {
            float w = bf2f(Wp[c * 128 + o]);
            #pragma unroll
            for (int i = 0; i < 16; ++i)
                acc[i] = fmaf(comb[half * 16 + i][c], w, acc[i]);
        }
    }
    #pragma unroll
    for (int i = 0; i < 16; ++i)
        hid[half * 16 + i][o] = tanhf(acc[i]);
    __syncthreads();

    const int q = t & 15, ar = t >> 4;   // ar in 0..15, handles agents ar and ar+16
    float l0, l1;
    if (isf) {
        const float* Wp = (const float*)W3;
        l0 = ((const float*)b3)[q]; l1 = l0;
        for (int oo = 0; oo < 128; ++oo) {
            float w = Wp[oo * 16 + q];
            l0 = fmaf(hid[ar][oo], w, l0);
            l1 = fmaf(hid[ar + 16][oo], w, l1);
        }
    } else {
        const unsigned short* Wp = (const unsigned short*)W3;
        l0 = bf2f(((const unsigned short*)b3)[q]); l1 = l0;
        for (int oo = 0; oo < 128; ++oo) {
            float w = bf2f(Wp[oo * 16 + q]);
            l0 = fmaf(hid[ar][oo], w, l0);
            l1 = fmaf(hid[ar + 16][oo], w, l1);
        }
    }
    size_t i0 = (size_t)(abase + ar) * 16 + q;
    size_t i1 = (size_t)(abase + ar + 16) * 16 + q;
    if (isf) {
        ((float*)out)[i0] = l0;
        ((float*)out)[i1] = l1;
    } else {
        ((unsigned short*)out)[i0] = f2bf(l0);
        ((unsigned short*)out)[i1] = f2bf(l1);
    }
}

extern "C" void kernel_launch(void* const* d_in, const int* in_sizes, int n_in,
                              void* d_out, int out_size, void* d_ws, size_t ws_size,
                              hipStream_t stream) {
    const void* obs = d_in[0];
    const int*  adj = (const int*)d_in[1];
    const void* W1  = d_in[2];
    const void* b1  = d_in[3];
    const void* W2  = d_in[4];
    const void* b2  = d_in[5];
    const void* W3  = d_in[6];
    const void* b3  = d_in[7];

    char* ws = (char*)d_ws;
    unsigned short* hT = (unsigned short*)(ws);                 // 144*8192*2  = 2,359,296 B
    float* h_f32 = (float*)(ws + 2359296);                      // 8192*128*4  = 4,194,304 B
    float* C     = (float*)(ws + 2359296 + 4194304);            // 8192*144*4  = 4,718,592 B
    int*   flag  = (int*)(ws + 2359296 + 4194304 + 4718592);    // 4 B

    hipLaunchKernelGGL(k0_init, dim3(1152), dim3(256), 0, stream, C, flag, (const unsigned short*)W1);
    hipLaunchKernelGGL(k1_encode, dim3(256), dim3(256), 0, stream, obs, W1, b1, flag, h_f32, hT);
    hipLaunchKernelGGL(k2_msggemm, dim3(512), dim3(256), 0, stream, adj, hT, C);
    hipLaunchKernelGGL(k3_actor, dim3(256), dim3(256), 0, stream, h_f32, C, W2, b2, W3, b3, flag, d_out);
}

// Round 3
// 515.484 us; speedup vs baseline: 1.1039x; 1.1039x over previous
//
#include <hip/hip_runtime.h>
#include <stdint.h>
#include <math.h>

#define NAG 8192
#define NB  144          // 128 feats + deg col(128) + pad to 9*16
#define LDA 72           // LDS row stride for A tile (64 + 8 pad shorts)
#define LDB 72           // LDS row stride for B tile

typedef __attribute__((ext_vector_type(8))) short short8;
typedef __attribute__((ext_vector_type(4))) float floatx4;

__device__ __forceinline__ float bf2f(unsigned short u) {
    union { uint32_t i; float f; } v; v.i = ((uint32_t)u) << 16; return v.f;
}
__device__ __forceinline__ unsigned short f2bf(float f) {
    union { float f; uint32_t i; } v; v.f = f;
    uint32_t x = v.i;
    return (unsigned short)((x + 0x7FFFu + ((x >> 16) & 1u)) >> 16);  // RNE
}

// ---------------- Kernel 0: zero C, detect float storage dtype from W1 raw bits ----------------
__global__ __launch_bounds__(256) void k0_init(
    float* __restrict__ C, int* __restrict__ flag,
    const unsigned short* __restrict__ W1raw)
{
    size_t i = ((size_t)blockIdx.x * 256 + threadIdx.x) * 4;   // 1152*256*4 = 8192*144 exactly
    *reinterpret_cast<float4*>(C + i) = make_float4(0.f, 0.f, 0.f, 0.f);
    if (blockIdx.x == 0 && threadIdx.x < 64) {
        int big = 0;
        #pragma unroll
        for (int j = 0; j < 8; ++j) {
            float v = bf2f(W1raw[threadIdx.x * 8 + j]);
            if (!(fabsf(v) <= 1e6f)) big = 1;   // catches huge and NaN
        }
        unsigned long long m = __ballot(big);
        if (threadIdx.x == 0) *flag = (m != 0ull) ? 1 : 0;
    }
}

// ---------------- Kernel 1: h = tanh(obs@W1+b1); write h_f32 and hT_bf16 ----------------
__global__ __launch_bounds__(256) void k1_encode(
    const void* __restrict__ obs,   // [8192][64] fp32 or bf16
    const void* __restrict__ W1,    // [64][128]
    const void* __restrict__ b1,    // [128]
    const int* __restrict__ flag,
    float* __restrict__ h_f32,      // [8192][128]
    unsigned short* __restrict__ hT)// [144][8192] bf16 (row128=ones, 129..143=0)
{
    __shared__ float obs_lds[32][68];
    __shared__ unsigned short ht_lds[128][33];
    const int t = threadIdx.x;
    const int abase = blockIdx.x * 32;
    const bool isf = (*flag != 0);

    {   // stage obs tile 32x64, 8 scalar elems/thread
        int a = t >> 3, c0 = (t & 7) * 8;
        if (isf) {
            const float* p = (const float*)obs;
            #pragma unroll
            for (int j = 0; j < 8; ++j)
                obs_lds[a][c0 + j] = p[(size_t)(abase + a) * 64 + c0 + j];
        } else {
            const unsigned short* p = (const unsigned short*)obs;
            #pragma unroll
            for (int j = 0; j < 8; ++j)
                obs_lds[a][c0 + j] = bf2f(p[(size_t)(abase + a) * 64 + c0 + j]);
        }
    }
    __syncthreads();

    const int o = t & 127;
    const int half = t >> 7;          // wave-uniform
    float acc[16];
    if (isf) {
        const float* Wp = (const float*)W1;
        float bias = ((const float*)b1)[o];
        #pragma unroll
        for (int i = 0; i < 16; ++i) acc[i] = bias;
        for (int k0 = 0; k0 < 64; k0 += 8) {
            float w[8];
            #pragma unroll
            for (int j = 0; j < 8; ++j) w[j] = Wp[(k0 + j) * 128 + o];
            #pragma unroll
            for (int j = 0; j < 8; ++j)
                #pragma unroll
                for (int i = 0; i < 16; ++i)
                    acc[i] = fmaf(obs_lds[half * 16 + i][k0 + j], w[j], acc[i]);
        }
    } else {
        const unsigned short* Wp = (const unsigned short*)W1;
        float bias = bf2f(((const unsigned short*)b1)[o]);
        #pragma unroll
        for (int i = 0; i < 16; ++i) acc[i] = bias;
        for (int k0 = 0; k0 < 64; k0 += 8) {
            float w[8];
            #pragma unroll
            for (int j = 0; j < 8; ++j) w[j] = bf2f(Wp[(k0 + j) * 128 + o]);
            #pragma unroll
            for (int j = 0; j < 8; ++j)
                #pragma unroll
                for (int i = 0; i < 16; ++i)
                    acc[i] = fmaf(obs_lds[half * 16 + i][k0 + j], w[j], acc[i]);
        }
    }
    #pragma unroll
    for (int i = 0; i < 16; ++i) {
        float th = tanhf(acc[i]);
        int a = half * 16 + i;
        h_f32[(size_t)(abase + a) * 128 + o] = th;
        ht_lds[o][a] = f2bf(th);
    }
    __syncthreads();

    for (int p = 0; p < 18; ++p) {
        int n = p * 8 + (t >> 5);
        int a = t & 31;
        unsigned short v;
        if (n < 128)       v = ht_lds[n][a];
        else if (n == 128) v = 0x3F80;     // 1.0 bf16 -> deg column
        else               v = 0;
        hT[(size_t)n * NAG + abase + a] = v;
    }
}

// ---------------- Kernel 2: C += adj[:, kslice] @ [h|1|0]  (bf16 MFMA, reg-prefetch pipeline) ----------------
__global__ __launch_bounds__(256, 4) void k2_msggemm(
    const int* __restrict__ adj,              // [8192][8192] int32 {0,1}
    const unsigned short* __restrict__ hT,    // [144][8192] bf16
    float* __restrict__ C)                    // [8192][144] fp32, pre-zeroed
{
    __shared__ __align__(16) unsigned short Alds[64 * LDA];
    __shared__ __align__(16) unsigned short Blds[NB * LDB];
    const int t = threadIdx.x;
    const int mtile = blockIdx.x & 127;       // 128 M-tiles of 64 rows
    const int ks = blockIdx.x >> 7;           // 8 K-splits of 1024
    const int row0 = mtile * 64;
    const int kbeg = ks * 1024;

    const int wave = t >> 6, lane = t & 63;
    const int fm = lane & 15, quad = lane >> 4;

    floatx4 acc[9];
    #pragma unroll
    for (int i = 0; i < 9; ++i) acc[i] = (floatx4)0.f;

    const int ar = t >> 2, aq = t & 3;    // A staging: row, quarter
    const int bln = t & 7, brow = t >> 3; // B staging: chunk-in-row, row-offset

    const int* aPtr = adj + (size_t)(row0 + ar) * NAG;
    int4 aReg[4];
    uint4 bReg[5];

    // initial prefetch (it = 0)
    #pragma unroll
    for (int i = 0; i < 4; ++i)
        aReg[i] = *reinterpret_cast<const int4*>(aPtr + kbeg + i * 16 + aq * 4);
    #pragma unroll
    for (int p = 0; p < 5; ++p) {
        int n = p * 32 + brow;
        if (n < NB)
            bReg[p] = *reinterpret_cast<const uint4*>(hT + (size_t)n * NAG + kbeg + bln * 8);
    }

    for (int it = 0; it < 16; ++it) {
        __syncthreads();   // previous compute finished before LDS overwrite
        #pragma unroll
        for (int i = 0; i < 4; ++i) {
            int c = i * 16 + aq * 4;
            uint32_t d0 = ((uint32_t)aReg[i].x | ((uint32_t)aReg[i].y << 16)) * 0x3F80u;
            uint32_t d1 = ((uint32_t)aReg[i].z | ((uint32_t)aReg[i].w << 16)) * 0x3F80u;
            *reinterpret_cast<uint2*>(&Alds[ar * LDA + c]) = make_uint2(d0, d1);
        }
        #pragma unroll
        for (int p = 0; p < 5; ++p) {
            int n = p * 32 + brow;
            if (n < NB)
                *reinterpret_cast<uint4*>(&Blds[n * LDB + bln * 8]) = bReg[p];
        }
        __syncthreads();
        if (it < 15) {     // issue next tile's loads; they drain at next iter's LDS write
            int kb = kbeg + (it + 1) * 64;
            #pragma unroll
            for (int i = 0; i < 4; ++i)
                aReg[i] = *reinterpret_cast<const int4*>(aPtr + kb + i * 16 + aq * 4);
            #pragma unroll
            for (int p = 0; p < 5; ++p) {
                int n = p * 32 + brow;
                if (n < NB)
                    bReg[p] = *reinterpret_cast<const uint4*>(hT + (size_t)n * NAG + kb + bln * 8);
            }
        }
        #pragma unroll
        for (int kk = 0; kk < 64; kk += 32) {
            short8 af = *reinterpret_cast<const short8*>(&Alds[(wave * 16 + fm) * LDA + kk + quad * 8]);
            #pragma unroll
            for (int nt = 0; nt < 9; ++nt) {
                short8 bf = *reinterpret_cast<const short8*>(&Blds[(nt * 16 + fm) * LDB + kk + quad * 8]);
                acc[nt] = __builtin_amdgcn_mfma_f32_16x16x32_bf16(af, bf, acc[nt], 0, 0, 0);
            }
        }
    }
    // epilogue: C/D layout col=lane&15, row=quad*4+reg; accumulate across 8 K-splits
    #pragma unroll
    for (int nt = 0; nt < 9; ++nt) {
        int col = nt * 16 + fm;
        #pragma unroll
        for (int r = 0; r < 4; ++r) {
            int row = row0 + wave * 16 + quad * 4 + r;
            atomicAdd(&C[(size_t)row * NB + col], acc[nt][r]);
        }
    }
}

// ---------------- Kernel 3: msg=sum/deg, actor MLP, dtype-adaptive ----------------
__global__ __launch_bounds__(256) void k3_actor(
    const float* __restrict__ h_f32,          // [8192][128]
    const float* __restrict__ C,              // [8192][144] fp32 sums
    const void* __restrict__ W2,              // [256][128]
    const void* __restrict__ b2,              // [128]
    const void* __restrict__ W3,              // [128][16]
    const void* __restrict__ b3,              // [16]
    const int* __restrict__ flag,
    void* __restrict__ out)                   // [8192][16]
{
    __shared__ float comb[32][256];
    __shared__ float hid[32][132];
    __shared__ float inv_lds[32];
    const int t = threadIdx.x;
    const int abase = blockIdx.x * 32;
    const bool isf = (*flag != 0);

    if (t < 32) {
        float deg = C[(size_t)(abase + t) * NB + 128];
        inv_lds[t] = 1.0f / fmaxf(deg, 1.0f);
    }
    __syncthreads();
    // parallel float4 staging: h part (32 agents x 32 float4)
    #pragma unroll
    for (int j = 0; j < 4; ++j) {
        int idx = j * 256 + t, a = idx >> 5, c = idx & 31;
        float4 v = *reinterpret_cast<const float4*>(h_f32 + (size_t)(abase + a) * 128 + c * 4);
        *reinterpret_cast<float4*>(&comb[a][c * 4]) = v;
    }
    // msg part (32 agents x 32 float4), scaled by 1/deg
    #pragma unroll
    for (int j = 0; j < 4; ++j) {
        int idx = j * 256 + t, a = idx >> 5, c = idx & 31;
        float4 v = *reinterpret_cast<const float4*>(C + (size_t)(abase + a) * NB + c * 4);
        float s = inv_lds[a];
        v.x *= s; v.y *= s; v.z *= s; v.w *= s;
        *reinterpret_cast<float4*>(&comb[a][128 + c * 4]) = v;
    }
    __syncthreads();

    const int o = t & 127, half = t >> 7;
    float acc[16];
    if (isf) {
        const float* Wp = (const float*)W2;
        float bias = ((const float*)b2)[o];
        #pragma unroll
        for (int i = 0; i < 16; ++i) acc[i] = bias;
        for (int c0 = 0; c0 < 256; c0 += 8) {
            float w[8];
            #pragma unroll
            for (int j = 0; j < 8; ++j) w[j] = Wp[(c0 + j) * 128 + o];
            #pragma unroll
            for (int j = 0; j < 8; ++j)
                #pragma unroll
                for (int i = 0; i < 16; ++i)
                    acc[i] = fmaf(comb[half * 16 + i][c0 + j], w[j], acc[i]);
        }
    } else {
        const unsigned short* Wp = (const unsigned short*)W2;
        float bias = bf2f(((const unsigned short*)b2)[o]);
        #pragma unroll
        for (int i = 0; i < 16; ++i) acc[i] = bias;
        for (int c0 = 0; c0 < 256; c0 += 8) {
            float w[8];
            #pragma unroll
            for (int j = 0; j < 8; ++j) w[j] = bf2f(Wp[(c0 + j) * 128 + o]);
            #pragma unroll
            for (int j = 0; j < 8; ++j)
                #pragma unroll
                for (int i = 0; i < 16; ++i)
                    acc[i] = fmaf(comb[half * 16 + i][c0 + j], w[j], acc[i]);
        }
    }
    #pragma unroll
    for (int i = 0; i < 16; ++i)
        hid[half * 16 + i][o] = tanhf(acc[i]);
    __syncthreads();

    const int q = t & 15, ar = t >> 4;   // agents ar and ar+16
    float l0, l1;
    if (isf) {
        const float* Wp = (const float*)W3;
        l0 = ((const float*)b3)[q]; l1 = l0;
        #pragma unroll 4
        for (int oo = 0; oo < 128; ++oo) {
            float w = Wp[oo * 16 + q];
            l0 = fmaf(hid[ar][oo], w, l0);
            l1 = fmaf(hid[ar + 16][oo], w, l1);
        }
    } else {
        const unsigned short* Wp = (const unsigned short*)W3;
        l0 = bf2f(((const unsigned short*)b3)[q]); l1 = l0;
        #pragma unroll 4
        for (int oo = 0; oo < 128; ++oo) {
            float w = bf2f(Wp[oo * 16 + q]);
            l0 = fmaf(hid[ar][oo], w, l0);
            l1 = fmaf(hid[ar + 16][oo], w, l1);
        }
    }
    size_t i0 = (size_t)(abase + ar) * 16 + q;
    size_t i1 = (size_t)(abase + ar + 16) * 16 + q;
    if (isf) {
        ((float*)out)[i0] = l0;
        ((float*)out)[i1] = l1;
    } else {
        ((unsigned short*)out)[i0] = f2bf(l0);
        ((unsigned short*)out)[i1] = f2bf(l1);
    }
}

extern "C" void kernel_launch(void* const* d_in, const int* in_sizes, int n_in,
                              void* d_out, int out_size, void* d_ws, size_t ws_size,
                              hipStream_t stream) {
    const void* obs = d_in[0];
    const int*  adj = (const int*)d_in[1];
    const void* W1  = d_in[2];
    const void* b1  = d_in[3];
    const void* W2  = d_in[4];
    const void* b2  = d_in[5];
    const void* W3  = d_in[6];
    const void* b3  = d_in[7];

    char* ws = (char*)d_ws;
    unsigned short* hT = (unsigned short*)(ws);                 // 2,359,296 B
    float* h_f32 = (float*)(ws + 2359296);                      // 4,194,304 B
    float* C     = (float*)(ws + 2359296 + 4194304);            // 4,718,592 B
    int*   flag  = (int*)(ws + 2359296 + 4194304 + 4718592);    // 4 B

    hipLaunchKernelGGL(k0_init, dim3(1152), dim3(256), 0, stream, C, flag, (const unsigned short*)W1);
    hipLaunchKernelGGL(k1_encode, dim3(256), dim3(256), 0, stream, obs, W1, b1, flag, h_f32, hT);
    hipLaunchKernelGGL(k2_msggemm, dim3(1024), dim3(256), 0, stream, adj, hT, C);
    hipLaunchKernelGGL(k3_actor, dim3(256), dim3(256), 0, stream, h_f32, C, W2, b2, W3, b3, flag, d_out);
}